// Round 1
// 277.686 us; speedup vs baseline: 1.0106x; 1.0106x over previous
//
#include <hip/hip_runtime.h>
#include <math.h>

// Problem constants: B=1, CIN=COUT=32, KS=3 (K=27), D=32, H=W=64, stride=1, pad=1, dil=1
#define DD 32
#define HH 64
#define WW 64
#define CSTRIDE (DD * HH * WW)   // 131072
#define NPOS (DD * HH * WW)

typedef __attribute__((ext_vector_type(8))) short  short8;   // 8 bf16 (4 VGPRs) MFMA A/B frag
typedef __attribute__((ext_vector_type(4))) float  float4v;  // MFMA C/D frag
typedef __attribute__((ext_vector_type(2))) float  f2v;      // packed-f32 pair
typedef __attribute__((ext_vector_type(4))) unsigned int uint4v;

__device__ __forceinline__ unsigned short f2bf(float f) {
    unsigned u = __builtin_bit_cast(unsigned, f);
    u = u + 0x7FFFu + ((u >> 16) & 1u);        // round-to-nearest-even
    return (unsigned short)(u >> 16);
}

// unpack one dword holding 2 bf16 -> f2v {lo, hi} (1 shift + 1 and)
__device__ __forceinline__ f2v bfpair(unsigned u) {
    f2v r;
    r.x = __builtin_bit_cast(float, u << 16);
    r.y = __builtin_bit_cast(float, u & 0xFFFF0000u);
    return r;
}

// ---------------------------------------------------------------------------
// prep_all: fused prep_x + prep_w (one launch instead of two).
//  blocks [0,512):    x[ci][pos] fp32 -> xT[pos][ci] bf16 (v_cvt_pk pairs)
//  blocks [512,998):  weight swizzles.
//  wAc channel order CHANGED vs previous version: ch' = tap_o*4 + comp,
//  comp in {oz,oy,ox,mask} -> phase-1 acc[mt] is directly the float4 of
//  tap mt*4+q, enabling b128 LDS traffic in the main kernel.
// ---------------------------------------------------------------------------
__global__ __launch_bounds__(256) void prep_all(
    const float* __restrict__ x, unsigned short* __restrict__ xT,
    const float* __restrict__ w_off, const float* __restrict__ w_mask,
    const float* __restrict__ w,
    unsigned short* __restrict__ wAc, unsigned short* __restrict__ wAe)
{
    if (blockIdx.x < NPOS / 256) {
        int pos = blockIdx.x * 256 + threadIdx.x;
        float v[32];
#pragma unroll
        for (int ci = 0; ci < 32; ci++) v[ci] = x[ci * CSTRIDE + pos];
        unsigned dw[16];
#pragma unroll
        for (int p = 0; p < 16; p++)
            asm("v_cvt_pk_bf16_f32 %0, %1, %2"
                : "=v"(dw[p]) : "v"(v[2 * p]), "v"(v[2 * p + 1]));
        uint4v* dst = (uint4v*)(xT + (size_t)pos * 32);
#pragma unroll
        for (int o = 0; o < 4; o++) {
            uint4v t4 = {dw[4 * o], dw[4 * o + 1], dw[4 * o + 2], dw[4 * o + 3]};
            dst[o] = t4;
        }
    } else {
        int i = (blockIdx.x - NPOS / 256) * 256 + threadIdx.x;
        if (i < 27 * 7 * 64 * 8) {                       // 96768: conv A-frags
            int j    = i & 7;
            int lane = (i >> 3) & 63;
            int fm   = i >> 9;
            int mt   = fm % 7;
            int tapw = fm / 7;                           // conv kernel tap
            int ch   = mt * 16 + (lane & 15);            // ch' = tap_o*4+comp
            int ci   = (lane >> 4) * 8 + j;
            float v = 0.f;
            if (ch < 108) {
                int tapo = ch >> 2, comp = ch & 3;
                v = (comp < 3) ? w_off[((comp * 27 + tapo) * 32 + ci) * 27 + tapw]
                               : w_mask[(tapo * 32 + ci) * 27 + tapw];
            }
            wAc[i] = f2bf(v);
        } else {                                         // 27648: einsum A-frags
            int i2   = i - 27 * 7 * 64 * 8;
            int j    = i2 & 7;
            int lane = (i2 >> 3) & 63;
            int fm   = i2 >> 9;
            int mt   = fm % 2;
            int tapw = fm / 2;
            int co   = mt * 16 + (lane & 15);
            int ci   = (lane >> 4) * 8 + j;
            wAe[i2] = f2bf(w[(co * 32 + ci) * 27 + tapw]);
        }
    }
}

// ---------------------------------------------------------------------------
// Phase-1 helper: issue all loads for one conv tap (B-frag + 7 A-frags).
// Invalid (z,y,x) handled by clamped address + zero-select (no continue, so
// the pair pipeline stays straight-line; only boundary blocks pay extra).
// ---------------------------------------------------------------------------
__device__ __forceinline__ void p1_issue(
    int tap, int d, int h, int wcol, int q, int lane,
    const unsigned short* __restrict__ xT, const unsigned short* __restrict__ wAc,
    short8& b, short8 (&a)[7])
{
    int kz = tap / 9; int r9 = tap - kz * 9; int ky = r9 / 3; int kx = r9 - ky * 3;
    int z = d + kz - 1, y = h + ky - 1, wx = wcol + kx - 1;
    bool ok = ((unsigned)z < (unsigned)DD) & ((unsigned)y < (unsigned)HH)
            & ((unsigned)wx < (unsigned)WW);
    int zc = min(max(z, 0), DD - 1);
    int yc = min(max(y, 0), HH - 1);
    int xc = min(max(wx, 0), WW - 1);
    int pos = (zc * HH + yc) * WW + xc;
    b = *(const short8*)(xT + (size_t)pos * 32 + q * 8);
    if (!ok) b = (short8)0;
    const unsigned short* ap = wAc + ((size_t)tap * 7 * 64 + lane) * 8;
#pragma unroll
    for (int mt = 0; mt < 7; mt++) a[mt] = *(const short8*)(ap + mt * 512);
}

// ---------------------------------------------------------------------------
// Phase-2 helper: per-tap address/weight math + issue the 8 corner gathers.
// Identical arithmetic to the previous version (same fma order, same clamps).
// ---------------------------------------------------------------------------
__device__ __forceinline__ void p2_prep(
    int tap, int d, int h, int wcol, float4v om,
    const unsigned short* __restrict__ xTq,
    float (&cw)[8], short8 (&cnr)[8])
{
    int kz = tap / 9; int r9 = tap - kz * 9; int ky = r9 / 3; int kx = r9 - ky * 3;
    float zc = (float)(d + kz - 1) + om.x;
    float yc = (float)(h + ky - 1) + om.y;
    float xc = (float)(wcol + kx - 1) + om.z;
    float m  = om.w;
    float zf = floorf(zc), yf = floorf(yc), xf = floorf(xc);
    int z0 = (int)zf, y0 = (int)yf, x0 = (int)xf;
    float fz = zc - zf, fy = yc - yf, fx = xc - xf;

    float wz0 = (z0 >= 0 && z0 < DD)         ? (1.f - fz) : 0.f;
    float wz1 = (z0 + 1 >= 0 && z0 + 1 < DD) ? fz         : 0.f;
    float wy0 = (y0 >= 0 && y0 < HH)         ? (1.f - fy) : 0.f;
    float wy1 = (y0 + 1 >= 0 && y0 + 1 < HH) ? fy         : 0.f;
    float wx0 = (x0 >= 0 && x0 < WW)         ? (1.f - fx) : 0.f;
    float wx1 = (x0 + 1 >= 0 && x0 + 1 < WW) ? fx         : 0.f;

    float mz0 = m * wz0, mz1 = m * wz1;
    float a00 = mz0 * wy0, a01 = mz0 * wy1, a10 = mz1 * wy0, a11 = mz1 * wy1;
    cw[0] = a00 * wx0; cw[1] = a00 * wx1; cw[2] = a01 * wx0; cw[3] = a01 * wx1;
    cw[4] = a10 * wx0; cw[5] = a10 * wx1; cw[6] = a11 * wx0; cw[7] = a11 * wx1;

    int iz0 = min(max(z0, 0), DD - 1), iz1 = min(max(z0 + 1, 0), DD - 1);
    int iy0 = min(max(y0, 0), HH - 1), iy1 = min(max(y0 + 1, 0), HH - 1);
    int ix0 = min(max(x0, 0), WW - 1), ix1 = min(max(x0 + 1, 0), WW - 1);
    int o00 = (iz0 * HH + iy0) * WW, o01 = (iz0 * HH + iy1) * WW;
    int o10 = (iz1 * HH + iy0) * WW, o11 = (iz1 * HH + iy1) * WW;

    cnr[0] = *(const short8*)(xTq + (o00 + ix0) * 32);
    cnr[1] = *(const short8*)(xTq + (o00 + ix1) * 32);
    cnr[2] = *(const short8*)(xTq + (o01 + ix0) * 32);
    cnr[3] = *(const short8*)(xTq + (o01 + ix1) * 32);
    cnr[4] = *(const short8*)(xTq + (o10 + ix0) * 32);
    cnr[5] = *(const short8*)(xTq + (o10 + ix1) * 32);
    cnr[6] = *(const short8*)(xTq + (o11 + ix0) * 32);
    cnr[7] = *(const short8*)(xTq + (o11 + ix1) * 32);
}

// ---------------------------------------------------------------------------
// Phase-2 pipelined step: consume tap t (buffers C), prefetch tap t+1 into
// buffers N. Next-tap gathers are issued BETWEEN the two 4-corner halves of
// the current tap's interpolation, so cnrC[0..3] are dead before cnrN goes
// in flight (keeps peak VGPR ~110).
// ---------------------------------------------------------------------------
__device__ __forceinline__ void p2_step(
    int t, int d, int h, int wcol, int wbase, const float* offm,
    const unsigned short* __restrict__ xTq,
    const unsigned short* __restrict__ wAe,
    float (&cwC)[8], short8 (&cnrC)[8],
    float (&cwN)[8], short8 (&cnrN)[8],
    float4v& ac0, float4v& ac1)
{
    const unsigned short* aep = wAe + ((size_t)t * 2 * 64) * 8;
    short8 a0 = *(const short8*)(aep);
    short8 a1 = *(const short8*)(aep + 512);

    bool pre = (t + 1 < 27);
    float4v omN;
    if (pre) omN = *(const float4v*)&offm[wbase + (t + 1) * 4];   // ds_read_b128

    f2v v0 = {0.f, 0.f}, v1 = {0.f, 0.f}, v2 = {0.f, 0.f}, v3 = {0.f, 0.f};

#define CORNER(c) {                                          \
        uint4v u = __builtin_bit_cast(uint4v, cnrC[c]);      \
        f2v w2; w2.x = cwC[c]; w2.y = cwC[c];                \
        v0 += bfpair(u.x) * w2;                              \
        v1 += bfpair(u.y) * w2;                              \
        v2 += bfpair(u.z) * w2;                              \
        v3 += bfpair(u.w) * w2; }

    CORNER(0) CORNER(1) CORNER(2) CORNER(3)                  // frees cnrC[0..3]

    if (pre) p2_prep(t + 1, d, h, wcol, omN, xTq, cwN, cnrN); // issue 8 gathers

    CORNER(4) CORNER(5) CORNER(6) CORNER(7)
#undef CORNER

    unsigned r0, r1, r2, r3;
    asm("v_cvt_pk_bf16_f32 %0, %1, %2" : "=v"(r0) : "v"(v0.x), "v"(v0.y));
    asm("v_cvt_pk_bf16_f32 %0, %1, %2" : "=v"(r1) : "v"(v1.x), "v"(v1.y));
    asm("v_cvt_pk_bf16_f32 %0, %1, %2" : "=v"(r2) : "v"(v2.x), "v"(v2.y));
    asm("v_cvt_pk_bf16_f32 %0, %1, %2" : "=v"(r3) : "v"(v3.x), "v"(v3.y));
    uint4v pr = {r0, r1, r2, r3};
    short8 bfr = __builtin_bit_cast(short8, pr);

    ac0 = __builtin_amdgcn_mfma_f32_16x16x32_bf16(a0, bfr, ac0, 0, 0, 0);
    ac1 = __builtin_amdgcn_mfma_f32_16x16x32_bf16(a1, bfr, ac1, 0, 0, 0);
}

// ---------------------------------------------------------------------------
// Main fused kernel. Block = 256 thr = 4 waves, one block per (d,h) row.
// Wave wv owns w-tile [wv*16, wv*16+16); lane l = (q<<4)|wl.  NO barriers:
// offm is [wcol][tap][comp] (float4-per-tap), columns are wave-private.
// ---------------------------------------------------------------------------
__global__ __launch_bounds__(256, 4) void deform_mfma_kernel(
    const unsigned short* __restrict__ xT,
    const unsigned short* __restrict__ wAc,
    const unsigned short* __restrict__ wAe,
    const float* __restrict__ b_off, const float* __restrict__ b_mask,
    const float* __restrict__ bias, float* __restrict__ out)
{
    __shared__ float offm[64 * 108];   // [wcol][tap][4], 27648 B

    const int t    = threadIdx.x;
    const int lane = t & 63;
    const int wv   = t >> 6;
    const int wl   = lane & 15;
    const int q    = lane >> 4;
    const int d    = blockIdx.x >> 6;
    const int h    = blockIdx.x & 63;
    const int wcol = wv * 16 + wl;
    const int wbase = wcol * 108;

    // ---------------- Phase 1: offset/mask conv via MFMA (pair-unrolled) ----
    float4v acc[7];
#pragma unroll
    for (int mt = 0; mt < 7; mt++) acc[mt] = (float4v){0.f, 0.f, 0.f, 0.f};

    {
        short8 b0, b1;
        short8 a0[7], a1[7];
        for (int tp = 0; tp < 27; tp += 2) {
            p1_issue(tp, d, h, wcol, q, lane, xT, wAc, b0, a0);
            bool two = (tp + 1 < 27);
            if (two) p1_issue(tp + 1, d, h, wcol, q, lane, xT, wAc, b1, a1);
#pragma unroll
            for (int mt = 0; mt < 7; mt++)
                acc[mt] = __builtin_amdgcn_mfma_f32_16x16x32_bf16(a0[mt], b0, acc[mt], 0, 0, 0);
            if (two) {
#pragma unroll
                for (int mt = 0; mt < 7; mt++)
                    acc[mt] = __builtin_amdgcn_mfma_f32_16x16x32_bf16(a1[mt], b1, acc[mt], 0, 0, 0);
            }
        }
    }

    // epilogue: acc[mt] IS the float4 {oz,oy,ox,mask-logit} of tap mt*4+q.
    // bias + sigmoid, one ds_write_b128 per tile. Sigmoid branch now uniform.
#pragma unroll
    for (int mt = 0; mt < 7; mt++) {
        int tapo = mt * 4 + q;
        if (tapo < 27) {                      // false only for mt=6, q=3
            float4v v = acc[mt];
            v.x += b_off[tapo];
            v.y += b_off[27 + tapo];
            v.z += b_off[54 + tapo];
            float mm = v.w + b_mask[tapo];
            v.w = 1.f / (1.f + __expf(-mm));
            *(float4v*)&offm[wbase + tapo * 4] = v;
        }
    }
    // no __syncthreads(): producers and consumers of each wcol column are in
    // the same wave; compiler orders same-wave LDS via lgkmcnt.

    // ---------------- Phase 2: pipelined sampling + einsum MFMA ------------
    const unsigned short* xTq = xT + q * 8;
    float4v ac0 = (float4v){0.f, 0.f, 0.f, 0.f};
    float4v ac1 = (float4v){0.f, 0.f, 0.f, 0.f};

    float cwA[8], cwB[8];
    short8 cnrA[8], cnrB[8];
    {
        float4v om0 = *(const float4v*)&offm[wbase];
        p2_prep(0, d, h, wcol, om0, xTq, cwA, cnrA);
    }
    const unsigned short* wAeL = wAe + (size_t)lane * 8;
    for (int tp = 0; tp < 27; tp += 2) {
        p2_step(tp,     d, h, wcol, wbase, offm, xTq, wAeL, cwA, cnrA, cwB, cnrB, ac0, ac1);
        if (tp + 1 >= 27) break;
        p2_step(tp + 1, d, h, wcol, wbase, offm, xTq, wAeL, cwB, cnrB, cwA, cnrA, ac0, ac1);
    }

    // ---------------- Epilogue: C/D layout -> global ----------------
    int sp = (d * HH + h) * WW + wcol;
#pragma unroll
    for (int r = 0; r < 4; r++) {
        int co0 = q * 4 + r;
        out[co0 * CSTRIDE + sp]        = ac0[r] + bias[co0];
        out[(16 + co0) * CSTRIDE + sp] = ac1[r] + bias[16 + co0];
    }
}

// ---------------------------------------------------------------------------
extern "C" void kernel_launch(void* const* d_in, const int* in_sizes, int n_in,
                              void* d_out, int out_size, void* d_ws, size_t ws_size,
                              hipStream_t stream) {
    const float* x      = (const float*)d_in[0];
    const float* w_off  = (const float*)d_in[1];
    const float* b_off  = (const float*)d_in[2];
    const float* w_mask = (const float*)d_in[3];
    const float* b_mask = (const float*)d_in[4];
    const float* w      = (const float*)d_in[5];
    const float* b      = (const float*)d_in[6];
    float* out = (float*)d_out;

    // workspace layout (all 16B aligned): xT 8,388,608 B | wAc 193,536 B | wAe 55,296 B
    unsigned short* xT  = (unsigned short*)d_ws;
    unsigned short* wAc = xT + (size_t)NPOS * 32;
    unsigned short* wAe = wAc + 27 * 7 * 64 * 8;

    // 512 blocks of x-transpose + 486 blocks of weight swizzle, one launch
    hipLaunchKernelGGL(prep_all, dim3(NPOS / 256 + 486), dim3(256), 0, stream,
                       x, xT, w_off, w_mask, w, wAc, wAe);
    hipLaunchKernelGGL(deform_mfma_kernel, dim3(DD * HH), dim3(256), 0, stream,
                       xT, wAc, wAe, b_off, b_mask, b, out);
}